// Round 16
// baseline (1637.792 us; speedup 1.0000x reference)
//
#include <hip/hip_runtime.h>

// ---------------------------------------------------------------------------
// AttentionDecoder. Laws:
//   R5: weights/state reads partitioned across blocks, never replicated.
//   R8: software grid barriers trash L2 -> never.
//   R9: LDS-staged MFMA (gload16) beats barrier-free direct-global MFMA.
//   R12: small matvecs: full LDS stage (all gload16 in flight) + ONE barrier.
//   R14: BK=64 double-chunk halves barrier drains.
//   R15: both-sides swizzle kills LDS bank conflicts (1.7e7 -> 0).
// R16: kv GEMM reads enc f32 DIRECTLY (reg-stage + pack + padded ds_write,
//   stride-40 A tile) -> enc segments dropped from mega-convert (~400 MB).
// ---------------------------------------------------------------------------

typedef float    f32x4 __attribute__((ext_vector_type(4)));
typedef __bf16   bf16x8 __attribute__((ext_vector_type(8)));
typedef unsigned short u16x8 __attribute__((ext_vector_type(8)));

#define DEV __device__ __forceinline__

DEV unsigned short f2bf(float f) {
  unsigned u = __builtin_bit_cast(unsigned, f);
  u += 0x7fffu + ((u >> 16) & 1u);
  return (unsigned short)(u >> 16);
}
DEV float bf2f(unsigned short h) {
  return __builtin_bit_cast(float, (unsigned)h << 16);
}
DEV bf16x8 as_bf(u16x8 v) { return __builtin_bit_cast(bf16x8, v); }
DEV u16x8 pack8(float4 a, float4 b) {
  u16x8 r;
  r[0]=f2bf(a.x); r[1]=f2bf(a.y); r[2]=f2bf(a.z); r[3]=f2bf(a.w);
  r[4]=f2bf(b.x); r[5]=f2bf(b.y); r[6]=f2bf(b.z); r[7]=f2bf(b.w);
  return r;
}
DEV void gload16(const void* g, void* l) {
  __builtin_amdgcn_global_load_lds(
      (const __attribute__((address_space(1))) void*)g,
      (__attribute__((address_space(3))) void*)l, 16, 0, 0);
}
DEV float gru1(float ir, float iz, float inn, float hr, float hz, float hn,
               float ho) {
  float r = 1.f / (1.f + expf(-(ir + hr)));
  float z = 1.f / (1.f + expf(-(iz + hz)));
  float n = tanhf(inn + r * hn);
  return (1.f - z) * n + z * ho;
}
// swizzled read offset within a [row][32]-elem chunk (gload16-staged tiles)
DEV int rdswz(int row, int fq) {
  return row * 32 + ((fq ^ ((row >> 1) & 3)) << 3);
}

// ----------------------- mega convert (one launch) --------------------------
#define NSEG 8
struct CvtSegs {
  const float* src[NSEG];
  unsigned short* dst[NSEG];
  int cum4[NSEG + 1];   // cumulative quad counts
};

__global__ __launch_bounds__(256) void k_cvt_multi(CvtSegs segs, int total4) {
  int i4 = blockIdx.x * 256 + threadIdx.x;
  if (i4 >= total4) return;
  int s = 0;
  while (i4 >= segs.cum4[s + 1]) s++;
  int off = (i4 - segs.cum4[s]) * 4;
  float4 v = *(const float4*)(segs.src[s] + off);
  unsigned short* d = segs.dst[s] + off;
  d[0] = f2bf(v.x); d[1] = f2bf(v.y); d[2] = f2bf(v.z); d[3] = f2bf(v.w);
}

// ctx_feat = [s1, s2, |s1-s2|, s1*s2]  -> bf16 [64, 16384]
__global__ __launch_bounds__(256) void k_build_ctx(const float* __restrict__ s1,
                                                   const float* __restrict__ s2,
                                                   unsigned short* __restrict__ ctx) {
  int j = blockIdx.x * 256 + threadIdx.x;
  int b = j >> 14, jj = j & 16383;
  int f = jj >> 12, k = jj & 4095;
  float a = s1[b * 4096 + k], c = s2[b * 4096 + k];
  float v = (f == 0) ? a : (f == 1) ? c : (f == 2) ? fabsf(a - c) : a * c;
  ctx[j] = f2bf(v);
}

// ---------------- fused kv GEMM: A = enc f32 direct, B bf16 gload16 ---------
// grid (128, 8): x = side*64 + row-block, y = col-block. EPI: tanh(+bias),
// split col 512, PERMUTED row store (tt*64+b -> b*128+tt).
// A tile: padded stride 40 (ds_write path, plain reads). B: gload16 + swizzle.
__global__ __launch_bounds__(256) void k_gemm_kv(
    const float* __restrict__ enc1f, const float* __restrict__ enc2f,
    const unsigned short* __restrict__ wkv1, const unsigned short* __restrict__ wkv2,
    unsigned short* __restrict__ keys1, unsigned short* __restrict__ vals1,
    unsigned short* __restrict__ keys2, unsigned short* __restrict__ vals2,
    const float* __restrict__ bk1, const float* __restrict__ bv1,
    const float* __restrict__ bk2, const float* __restrict__ bv2)
{
  __shared__ __align__(16) unsigned short As2[2][128 * 40];   // 20 KB, pad 8
  __shared__ __align__(16) unsigned short Bs[2][128 * 32];    // 16 KB
  const int tid = threadIdx.x;
  const int side = blockIdx.x >> 6;
  const int r0 = (blockIdx.x & 63) * 128, c0 = blockIdx.y * 128;
  const float* Af = side ? enc2f : enc1f;
  const unsigned short* B = side ? wkv2 : wkv1;
  unsigned short* kout = side ? keys2 : keys1;
  unsigned short* vout = side ? vals2 : vals1;
  const float* bk = side ? bk2 : bk1;
  const float* bv = side ? bv2 : bv1;

  const int lane = tid & 63, w = tid >> 6;
  const int wr = w >> 1, wc = w & 1;
  const int fr = lane & 15, fq = lane >> 4;
  f32x4 acc[4][4] = {};

  const int srow = tid >> 2, q8 = (tid & 3) * 8;
  const int scolB = ((tid & 3) ^ ((srow >> 1) & 3)) * 8;     // B src swizzle
  const float* gAf0 = Af + (size_t)(r0 + srow) * 4096 + q8;
  const float* gAf1 = Af + (size_t)(r0 + 64 + srow) * 4096 + q8;
  const unsigned short* gB0 = B + (size_t)(c0 + srow) * 4096 + scolB;
  const unsigned short* gB1 = B + (size_t)(c0 + 64 + srow) * 4096 + scolB;

  for (int k = 0; k < 4096; k += 64) {
    // issue f32 A loads first (latency under gload16s + pack)
    float4 a00 = *(const float4*)(gAf0 + k);
    float4 a01 = *(const float4*)(gAf0 + k + 4);
    float4 a02 = *(const float4*)(gAf0 + k + 32);
    float4 a03 = *(const float4*)(gAf0 + k + 36);
    float4 a10 = *(const float4*)(gAf1 + k);
    float4 a11 = *(const float4*)(gAf1 + k + 4);
    float4 a12 = *(const float4*)(gAf1 + k + 32);
    float4 a13 = *(const float4*)(gAf1 + k + 36);
    gload16(gB0 + k, Bs[0] + tid * 8);
    gload16(gB0 + k + 32, Bs[1] + tid * 8);
    gload16(gB1 + k, Bs[0] + 2048 + tid * 8);
    gload16(gB1 + k + 32, Bs[1] + 2048 + tid * 8);

    *(u16x8*)&As2[0][srow * 40 + q8]        = pack8(a00, a01);
    *(u16x8*)&As2[1][srow * 40 + q8]        = pack8(a02, a03);
    *(u16x8*)&As2[0][(64 + srow) * 40 + q8] = pack8(a10, a11);
    *(u16x8*)&As2[1][(64 + srow) * 40 + q8] = pack8(a12, a13);
    __syncthreads();

    #pragma unroll
    for (int c = 0; c < 2; c++) {
      u16x8 af[4], bfv[4];
      #pragma unroll
      for (int mi = 0; mi < 4; mi++)
        af[mi] = *(const u16x8*)&As2[c][(wr * 64 + mi * 16 + fr) * 40 + fq * 8];
      #pragma unroll
      for (int nj = 0; nj < 4; nj++)
        bfv[nj] = *(const u16x8*)&Bs[c][rdswz(wc * 64 + nj * 16 + fr, fq)];
      #pragma unroll
      for (int mi = 0; mi < 4; mi++)
        #pragma unroll
        for (int nj = 0; nj < 4; nj++)
          acc[mi][nj] = __builtin_amdgcn_mfma_f32_16x16x32_bf16(
              as_bf(af[mi]), as_bf(bfv[nj]), acc[mi][nj], 0, 0, 0);
    }
    __syncthreads();
  }

  #pragma unroll
  for (int mi = 0; mi < 4; mi++)
  #pragma unroll
  for (int nj = 0; nj < 4; nj++) {
    f32x4 a = acc[mi][nj];
    #pragma unroll
    for (int j = 0; j < 4; j++) {
      int grow = r0 + wr * 64 + mi * 16 + fq * 4 + j;
      int gcol = c0 + wc * 64 + nj * 16 + fr;
      float bias = gcol < 512 ? bk[gcol] : bv[gcol - 512];
      unsigned short r = f2bf(tanhf(a[j] + bias));
      int prow = ((grow & 63) << 7) | (grow >> 6);
      (gcol < 512 ? kout : vout)[(size_t)prow * 512 + (gcol & 511)] = r;
    }
  }
}

// ---------------- vocab GEMM, XCD remap + BK=64 + swizzle -------------------
__global__ __launch_bounds__(256) void k_gemm_voc(
    const unsigned short* __restrict__ A,       // outs_bf [2048][512]
    const unsigned short* __restrict__ B,       // wvoc [32000][512]
    float* __restrict__ of, const float* __restrict__ bias)
{
  const int L = blockIdx.x;
  const int xcd = L & 7, k = L >> 3;
  const int rb = k & 15, cb = xcd * 32 + (k >> 4);
  if (cb >= 250) return;
  const int r0 = rb * 128, c0 = cb * 128;

  __shared__ __align__(16) unsigned short As[2][128 * 32];
  __shared__ __align__(16) unsigned short Bs[2][128 * 32];
  const int tid = threadIdx.x;
  const int lane = tid & 63, w = tid >> 6;
  const int wr = w >> 1, wc = w & 1;
  const int fr = lane & 15, fq = lane >> 4;
  f32x4 acc[4][4] = {};

  const int srow = tid >> 2;
  const int scol = ((tid & 3) ^ ((srow >> 1) & 3)) * 8;
  const unsigned short* gA0 = A + (size_t)(r0 + srow) * 512 + scol;
  const unsigned short* gA1 = A + (size_t)(r0 + 64 + srow) * 512 + scol;
  const unsigned short* gB0 = B + (size_t)(c0 + srow) * 512 + scol;
  const unsigned short* gB1 = B + (size_t)(c0 + 64 + srow) * 512 + scol;

  for (int kk = 0; kk < 512; kk += 64) {
    #pragma unroll
    for (int c = 0; c < 2; c++) {
      gload16(gA0 + kk + c * 32, As[c] + tid * 8);
      gload16(gA1 + kk + c * 32, As[c] + 2048 + tid * 8);
      gload16(gB0 + kk + c * 32, Bs[c] + tid * 8);
      gload16(gB1 + kk + c * 32, Bs[c] + 2048 + tid * 8);
    }
    __syncthreads();

    #pragma unroll
    for (int c = 0; c < 2; c++) {
      u16x8 af[4], bfv[4];
      #pragma unroll
      for (int mi = 0; mi < 4; mi++)
        af[mi] = *(const u16x8*)&As[c][rdswz(wr * 64 + mi * 16 + fr, fq)];
      #pragma unroll
      for (int nj = 0; nj < 4; nj++)
        bfv[nj] = *(const u16x8*)&Bs[c][rdswz(wc * 64 + nj * 16 + fr, fq)];
      #pragma unroll
      for (int mi = 0; mi < 4; mi++)
        #pragma unroll
        for (int nj = 0; nj < 4; nj++)
          acc[mi][nj] = __builtin_amdgcn_mfma_f32_16x16x32_bf16(
              as_bf(af[mi]), as_bf(bfv[nj]), acc[mi][nj], 0, 0, 0);
    }
    __syncthreads();
  }

  #pragma unroll
  for (int mi = 0; mi < 4; mi++)
  #pragma unroll
  for (int nj = 0; nj < 4; nj++) {
    f32x4 a = acc[mi][nj];
    #pragma unroll
    for (int j = 0; j < 4; j++) {
      int grow = r0 + wr * 64 + mi * 16 + fq * 4 + j;
      int gcol = c0 + wc * 64 + nj * 16 + fr;
      of[(size_t)grow * 32000 + gcol] = a[j] + bias[gcol];
    }
  }
}

// ------------------------- h0 GEMM (A bf16, B f32) --------------------------
__global__ __launch_bounds__(256) void k_gemm_h0(
    const unsigned short* __restrict__ Ap, int lda, const float* __restrict__ Bp,
    int ldb, int M, int N, int kper, float* __restrict__ of)
{
  __shared__ __align__(16) unsigned short As[128 * 32];
  __shared__ __align__(16) unsigned short Bs[128 * 32];
  const int tid = threadIdx.x;
  const int c0 = blockIdx.x * 128, r0 = blockIdx.y * 128;
  const int k0 = blockIdx.z * kper;
  of += (size_t)blockIdx.z * M * N;

  const int lane = tid & 63, w = tid >> 6;
  const int wr = w >> 1, wc = w & 1;
  const int fr = lane & 15, fq = lane >> 4;
  f32x4 acc[4][4] = {};
  const int srow = tid >> 1, shalf = (tid & 1) * 16;

  for (int k = k0; k < k0 + kper; k += 32) {
    u16x8 a0, a1, b0, b1;
    {
      int gr = r0 + srow;
      if (gr < M) {
        const unsigned short* a = Ap + (size_t)gr * lda + k + shalf;
        a0 = *(const u16x8*)a; a1 = *(const u16x8*)(a + 8);
      } else {
        u16x8 z = {0,0,0,0,0,0,0,0}; a0 = z; a1 = z;
      }
    }
    {
      int gr = c0 + srow;
      const float* p = Bp + (size_t)gr * ldb + k + shalf;
      float4 f0 = ((const float4*)p)[0], f1 = ((const float4*)p)[1];
      float4 f2 = ((const float4*)p)[2], f3 = ((const float4*)p)[3];
      b0 = pack8(f0, f1);
      b1 = pack8(f2, f3);
    }
    *(u16x8*)&As[srow * 32 + shalf]     = a0;
    *(u16x8*)&As[srow * 32 + shalf + 8] = a1;
    *(u16x8*)&Bs[srow * 32 + shalf]     = b0;
    *(u16x8*)&Bs[srow * 32 + shalf + 8] = b1;
    __syncthreads();

    u16x8 af[4], bfv[4];
    #pragma unroll
    for (int mi = 0; mi < 4; mi++)
      af[mi] = *(const u16x8*)&As[(wr * 64 + mi * 16 + fr) * 32 + fq * 8];
    #pragma unroll
    for (int nj = 0; nj < 4; nj++)
      bfv[nj] = *(const u16x8*)&Bs[(wc * 64 + nj * 16 + fr) * 32 + fq * 8];
    #pragma unroll
    for (int mi = 0; mi < 4; mi++)
      #pragma unroll
      for (int nj = 0; nj < 4; nj++)
        acc[mi][nj] = __builtin_amdgcn_mfma_f32_16x16x32_bf16(
            as_bf(af[mi]), as_bf(bfv[nj]), acc[mi][nj], 0, 0, 0);
    __syncthreads();
  }

  #pragma unroll
  for (int mi = 0; mi < 4; mi++)
  #pragma unroll
  for (int nj = 0; nj < 4; nj++) {
    f32x4 a = acc[mi][nj];
    #pragma unroll
    for (int j = 0; j < 4; j++) {
      int grow = r0 + wr * 64 + mi * 16 + fq * 4 + j;
      int gcol = c0 + wc * 64 + nj * 16 + fr;
      if (grow < M) of[(size_t)grow * N + gcol] = a[j];
    }
  }
}

__global__ __launch_bounds__(256) void k_reduce_h0(const float* __restrict__ part,
                                                   const float* __restrict__ b_ctx,
                                                   float* __restrict__ h,
                                                   unsigned short* __restrict__ h_bf) {
  int j = blockIdx.x * 256 + threadIdx.x;   // < 64*512
  float s = b_ctx[j & 511];
  for (int z = 0; z < 8; z++) s += part[z * 32768 + j];
  h[j] = s;
  h_bf[j] = f2bf(s);
}

// ------------------- W_f = W_ih @ W_in  fold (one-time) ---------------------
__global__ __launch_bounds__(256) void k_wf(const float* __restrict__ W_ih,
                                            const float* __restrict__ W_in,
                                            unsigned short* __restrict__ wf_att,
                                            float* __restrict__ wfx) {
  __shared__ float wl[8][512];
  int ic = blockIdx.x, jc = blockIdx.y, tid = threadIdx.x;
  for (int x = tid; x < 8 * 512; x += 256)
    wl[x >> 9][x & 511] = W_ih[(ic * 8 + (x >> 9)) * 512 + (x & 511)];
  __syncthreads();
  int j = jc * 256 + tid;
  if (j >= 1324) return;
  float acc[8] = {};
  for (int d = 0; d < 512; d++) {
    float win = W_in[d * 1324 + j];
    #pragma unroll
    for (int r = 0; r < 8; r++) acc[r] += wl[r][d] * win;
  }
  for (int r = 0; r < 8; r++) {
    int i = ic * 8 + r;
    if (j < 300) wfx[i * 300 + j] = acc[r];
    else         wf_att[i * 1024 + (j - 300)] = f2bf(acc[r]);
  }
}

__global__ __launch_bounds__(256) void k_bfull(const float* __restrict__ W_ih,
                                               const float* __restrict__ b_in,
                                               const float* __restrict__ b_ih,
                                               float* __restrict__ bfull) {
  int i = blockIdx.x * 256 + threadIdx.x;
  if (i >= 1536) return;
  float acc = b_ih[i];
  for (int d = 0; d < 512; d++) acc += W_ih[i * 512 + d] * b_in[d];
  bfull[i] = acc;
}

// gi_x[t*64+b, :] = expl[t,b,:300] @ Wfx^T
__global__ __launch_bounds__(256) void k_gix(const float* __restrict__ expl,
                                             const float* __restrict__ wfx,
                                             float* __restrict__ gi_x) {
  __shared__ float el[16][300];
  int rc = blockIdx.x, ic = blockIdx.y, tid = threadIdx.x;
  for (int x = tid; x < 16 * 300; x += 256)
    el[x / 300][x % 300] = expl[(size_t)(rc * 16 + x / 300) * 300 + (x % 300)];
  __syncthreads();
  int c = ic * 256 + tid;
  float acc[16] = {};
  for (int k = 0; k < 300; k++) {
    float wv = wfx[c * 300 + k];
    #pragma unroll
    for (int r = 0; r < 16; r++) acc[r] += el[r][k] * wv;
  }
  for (int r = 0; r < 16; r++) gi_x[(size_t)(rc * 16 + r) * 1536 + c] = acc[r];
}

// ---- S1: [q|gh] matvec, fully staged + swizzle, ONE barrier ----------------
__global__ __launch_bounds__(256) void k_mv64f(
    const unsigned short* __restrict__ A,      // h_bf [64][512]
    const unsigned short* __restrict__ B,      // wcat [2560][512]
    const float* __restrict__ bq1, const float* __restrict__ bq2,
    const float* __restrict__ b_hh,
    float* __restrict__ qf, float* __restrict__ ghf)
{
  __shared__ __align__(16) unsigned short AL[16 * 2048];   // 64KB
  __shared__ __align__(16) unsigned short BL[16 * 2048];   // 64KB
  const int tid = threadIdx.x;
  const int n0 = blockIdx.x * 64;
  const int srow = tid >> 2;
  const int scol = ((tid & 3) ^ ((srow >> 1) & 3)) * 8;

  #pragma unroll
  for (int c = 0; c < 16; c++) {
    gload16(A + (size_t)srow * 512 + c * 32 + scol, AL + c * 2048 + tid * 8);
    gload16(B + (size_t)(n0 + srow) * 512 + c * 32 + scol, BL + c * 2048 + tid * 8);
  }
  __syncthreads();

  const int lane = tid & 63, w = tid >> 6;
  const int fr = lane & 15, fq = lane >> 4;
  f32x4 acc[4] = {};
  #pragma unroll
  for (int c = 0; c < 16; c++) {
    u16x8 af = *(const u16x8*)(AL + c * 2048 + rdswz(w * 16 + fr, fq));
    #pragma unroll
    for (int nj = 0; nj < 4; nj++) {
      u16x8 bv = *(const u16x8*)(BL + c * 2048 + rdswz(nj * 16 + fr, fq));
      acc[nj] = __builtin_amdgcn_mfma_f32_16x16x32_bf16(as_bf(af), as_bf(bv), acc[nj], 0, 0, 0);
    }
  }
  #pragma unroll
  for (int nj = 0; nj < 4; nj++) {
    #pragma unroll
    for (int j = 0; j < 4; j++) {
      int row = w * 16 + fq * 4 + j;
      int col = n0 + nj * 16 + fr;
      float v = acc[nj][j];
      if (col < 512)       qf[(size_t)row * 1024 + col] = tanhf(v + bq1[col]);
      else if (col < 1024) qf[(size_t)row * 1024 + col] = tanhf(v + bq2[col - 512]);
      else                 ghf[(size_t)row * 1536 + (col - 1024)] = v + b_hh[col - 1024];
    }
  }
}

// ------------------- S2: attention (R6 verbatim) ----------------------------
__global__ __launch_bounds__(256) void k_att(
    const float* __restrict__ qf,
    const unsigned short* __restrict__ keys1, const unsigned short* __restrict__ keys2,
    const unsigned short* __restrict__ vals1, const unsigned short* __restrict__ vals2,
    unsigned short* __restrict__ att_bf)
{
  const int id = blockIdx.x, side = id >> 6, b = id & 63;
  const int tid = threadIdx.x;
  __shared__ float qv[512];
  __shared__ float sred[128][2];
  __shared__ float pr[128];

  for (int i = tid; i < 512; i += 256)
    qv[i] = qf[(size_t)b * 1024 + side * 512 + i];
  __syncthreads();

  const unsigned short* keys = side ? keys2 : keys1;
  {
    int tt = tid >> 1, half = tid & 1;
    const u16x8* krow = (const u16x8*)(keys + ((size_t)(b * 128 + tt)) * 512 + half * 256);
    float acc = 0.f;
    #pragma unroll 4
    for (int k8 = 0; k8 < 32; k8++) {
      u16x8 kv = krow[k8];
      #pragma unroll
      for (int jj = 0; jj < 8; jj++) acc += qv[half * 256 + k8 * 8 + jj] * bf2f(kv[jj]);
    }
    sred[tt][half] = acc;
  }
  __syncthreads();

  if (tid < 64) {
    float s0 = sred[tid][0] + sred[tid][1];
    float s1 = sred[tid + 64][0] + sred[tid + 64][1];
    float m = fmaxf(s0, s1);
    #pragma unroll
    for (int off = 32; off; off >>= 1) m = fmaxf(m, __shfl_xor(m, off));
    float e0 = __expf(s0 - m), e1 = __expf(s1 - m);
    float ss = e0 + e1;
    #pragma unroll
    for (int off = 32; off; off >>= 1) ss += __shfl_xor(ss, off);
    float inv = 1.f / ss;
    pr[tid] = e0 * inv;
    pr[tid + 64] = e1 * inv;
  }
  __syncthreads();

  const unsigned short* vals = side ? vals2 : vals1;
  {
    int a0 = tid * 2;
    float acc0 = 0.f, acc1 = 0.f;
    for (int tt = 0; tt < 128; tt++) {
      float p = pr[tt];
      unsigned v = *(const unsigned*)(vals + ((size_t)(b * 128 + tt)) * 512 + a0);
      acc0 += p * bf2f((unsigned short)(v & 0xffffu));
      acc1 += p * bf2f((unsigned short)(v >> 16));
    }
    att_bf[(size_t)b * 1024 + side * 512 + a0]     = f2bf(acc0);
    att_bf[(size_t)b * 1024 + side * 512 + a0 + 1] = f2bf(acc1);
  }
}

// ---- S3: gi partials, split-K (2x24), fully staged + swizzle ---------------
__global__ __launch_bounds__(256) void k_giK(
    const unsigned short* __restrict__ att_bf,   // [64][1024]
    const unsigned short* __restrict__ wf_att,   // [1536][1024]
    float* __restrict__ gip)
{
  __shared__ __align__(16) unsigned short AL[16 * 2048];
  __shared__ __align__(16) unsigned short BL[16 * 2048];
  const int tid = threadIdx.x;
  const int j = blockIdx.x % 24, kh = blockIdx.x / 24;
  const int n0 = j * 64, k0 = kh * 512;
  const int srow = tid >> 2;
  const int scol = ((tid & 3) ^ ((srow >> 1) & 3)) * 8;

  #pragma unroll
  for (int c = 0; c < 16; c++) {
    gload16(att_bf + (size_t)srow * 1024 + k0 + c * 32 + scol, AL + c * 2048 + tid * 8);
    gload16(wf_att + (size_t)(n0 + srow) * 1024 + k0 + c * 32 + scol, BL + c * 2048 + tid * 8);
  }
  __syncthreads();

  const int lane = tid & 63, w = tid >> 6;
  const int fr = lane & 15, fq = lane >> 4;
  f32x4 acc[4] = {};
  #pragma unroll
  for (int c = 0; c < 16; c++) {
    u16x8 af = *(const u16x8*)(AL + c * 2048 + rdswz(w * 16 + fr, fq));
    #pragma unroll
    for (int nj = 0; nj < 4; nj++) {
      u16x8 bv = *(const u16x8*)(BL + c * 2048 + rdswz(nj * 16 + fr, fq));
      acc[nj] = __builtin_amdgcn_mfma_f32_16x16x32_bf16(as_bf(af), as_bf(bv), acc[nj], 0, 0, 0);
    }
  }
  #pragma unroll
  for (int nj = 0; nj < 4; nj++) {
    #pragma unroll
    for (int jj = 0; jj < 4; jj++) {
      int row = w * 16 + fq * 4 + jj;
      int col = n0 + nj * 16 + fr;
      gip[(size_t)(kh * 64 + row) * 1536 + col] = acc[nj][jj];
    }
  }
}

// ---- S4: combine partials + GRU (R12 verbatim) -----------------------------
__global__ __launch_bounds__(512) void k_gru2(
    int t, const float* __restrict__ gip, const float* __restrict__ gi_x,
    const float* __restrict__ bfull, const float* __restrict__ ghf,
    float* __restrict__ hst, unsigned short* __restrict__ h_bf,
    unsigned short* __restrict__ outs_bf)
{
  const int b = blockIdx.x, d = threadIdx.x;
  size_t gb = (size_t)(t * 64 + b) * 1536;
  float ir = gip[(size_t)b * 1536 + d] + gip[(size_t)(64 + b) * 1536 + d]
           + gi_x[gb + d] + bfull[d];
  float iz = gip[(size_t)b * 1536 + 512 + d] + gip[(size_t)(64 + b) * 1536 + 512 + d]
           + gi_x[gb + 512 + d] + bfull[512 + d];
  float inn = gip[(size_t)b * 1536 + 1024 + d] + gip[(size_t)(64 + b) * 1536 + 1024 + d]
           + gi_x[gb + 1024 + d] + bfull[1024 + d];
  float hv = gru1(ir, iz, inn,
                  ghf[b * 1536 + d], ghf[b * 1536 + 512 + d], ghf[b * 1536 + 1024 + d],
                  hst[b * 512 + d]);
  hst[b * 512 + d] = hv;
  unsigned short bf = f2bf(hv);
  h_bf[b * 512 + d] = bf;
  outs_bf[(size_t)(t * 64 + b) * 512 + d] = bf;
}

// ---------------------------------------------------------------------------
extern "C" void kernel_launch(void* const* d_in, const int* in_sizes, int n_in,
                              void* d_out, int out_size, void* d_ws, size_t ws_size,
                              hipStream_t stream) {
  const float* expl  = (const float*)d_in[0];
  const float* enc1  = (const float*)d_in[1];
  const float* enc2  = (const float*)d_in[2];
  const float* s1e   = (const float*)d_in[3];
  const float* s2e   = (const float*)d_in[4];
  const float* W_ctx = (const float*)d_in[5];
  const float* b_ctx = (const float*)d_in[6];
  const float* Wq1   = (const float*)d_in[7];
  const float* bq1   = (const float*)d_in[8];
  const float* Wk1   = (const float*)d_in[9];
  const float* bk1   = (const float*)d_in[10];
  const float* Wv1   = (const float*)d_in[11];
  const float* bv1   = (const float*)d_in[12];
  const float* Wq2   = (const float*)d_in[13];
  const float* bq2   = (const float*)d_in[14];
  const float* Wk2   = (const float*)d_in[15];
  const float* bk2   = (const float*)d_in[16];
  const float* Wv2   = (const float*)d_in[17];
  const float* bv2   = (const float*)d_in[18];
  const float* W_in  = (const float*)d_in[19];
  const float* b_in  = (const float*)d_in[20];
  const float* W_ih  = (const float*)d_in[21];
  const float* b_ih  = (const float*)d_in[22];
  const float* W_hh  = (const float*)d_in[23];
  const float* b_hh  = (const float*)d_in[24];
  const float* W_voc = (const float*)d_in[25];
  const float* b_voc = (const float*)d_in[26];
  float* out = (float*)d_out;

  char* ws = (char*)d_ws;
  unsigned short* keys1  = (unsigned short*)(ws + 0);
  unsigned short* vals1  = (unsigned short*)(ws + 8388608);
  unsigned short* keys2  = (unsigned short*)(ws + 16777216);
  unsigned short* vals2  = (unsigned short*)(ws + 25165824);
  unsigned short* wkv1   = (unsigned short*)(ws + 167772160);  // 8.4 MB
  unsigned short* wkv2   = (unsigned short*)(ws + 176160768);  // 8.4 MB
  unsigned short* wvoc   = (unsigned short*)(ws + 184549376);  // 32.8 MB
  unsigned short* wcat   = (unsigned short*)(ws + 217317376);  // [2560][512]
  unsigned short* wf_att = (unsigned short*)(ws + 219938816);  // [1536][1024]
  float*          wfx    = (float*)(ws + 223084544);
  float*          bfull  = (float*)(ws + 224927744);
  float*          gi_x   = (float*)(ws + 224933888);           // 12.6 MB
  unsigned short* ctx_bf = (unsigned short*)(ws + 237516800);
  float*          part   = (float*)(ws + 239613952);
  float*          hst    = (float*)(ws + 240662528);
  unsigned short* h_bf   = (unsigned short*)(ws + 240793600);
  float*          qf     = (float*)(ws + 240859136);
  float*          ghf    = (float*)(ws + 241121280);
  unsigned short* att_bf = (unsigned short*)(ws + 241514496);
  unsigned short* outs_bf= (unsigned short*)(ws + 241645568);
  float*          gip    = (float*)(ws + 243742720);
  // end ~244.5 MB

  // ---- ONE mega-convert (weights only; enc read f32 directly by kv) ----
  {
    CvtSegs segs;
    const float* srcs[NSEG] = { Wk1, Wv1, Wk2, Wv2, W_voc, Wq1, Wq2, W_hh };
    unsigned short* dsts[NSEG] = { wkv1, wkv1 + 512*4096, wkv2, wkv2 + 512*4096,
                                   wvoc, wcat, wcat + 512*512, wcat + 1024*512 };
    int ns[NSEG] = { 512*4096, 512*4096, 512*4096, 512*4096,
                     32000*512, 512*512, 512*512, 1536*512 };
    int cum = 0;
    for (int s = 0; s < NSEG; s++) {
      segs.src[s] = srcs[s]; segs.dst[s] = dsts[s];
      segs.cum4[s] = cum; cum += ns[s] / 4;
    }
    segs.cum4[NSEG] = cum;
    k_cvt_multi<<<(cum + 255) / 256, 256, 0, stream>>>(segs, cum);
  }

  // ---- fused kv GEMM (enc f32 direct, BK=64 + swizzle) ----
  k_gemm_kv<<<dim3(128, 8), 256, 0, stream>>>(
      enc1, enc2, wkv1, wkv2, keys1, vals1, keys2, vals2,
      bk1, bv1, bk2, bv2);

  // ---- Wf fold + gi_x ----
  k_wf<<<dim3(192, 6), 256, 0, stream>>>(W_ih, W_in, wf_att, wfx);
  k_bfull<<<6, 256, 0, stream>>>(W_ih, b_in, b_ih, bfull);
  k_gix<<<dim3(128, 6), 256, 0, stream>>>(expl, wfx, gi_x);

  // ---- h0 ----
  k_build_ctx<<<4096, 256, 0, stream>>>(s1e, s2e, ctx_bf);
  k_gemm_h0<<<dim3(4, 1, 8), 256, 0, stream>>>(
      ctx_bf, 16384, W_ctx, 16384, 64, 512, 2048, part);
  k_reduce_h0<<<128, 256, 0, stream>>>(part, b_ctx, hst, h_bf);

  // ---- recurrence: 4 launches per step (R12 chain + swizzle) ----
  for (int t = 0; t < 32; t++) {
    k_mv64f<<<40, 256, 0, stream>>>(h_bf, wcat, bq1, bq2, b_hh, qf, ghf);
    k_att<<<128, 256, 0, stream>>>(qf, keys1, keys2, vals1, vals2, att_bf);
    k_giK<<<48, 256, 0, stream>>>(att_bf, wf_att, gip);
    k_gru2<<<64, 512, 0, stream>>>(t, gip, gi_x, bfull, ghf, hst, h_bf, outs_bf);
  }

  // ---- logits = outs @ W_voc^T + b_voc (XCD-remapped, BK=64 + swizzle) ----
  k_gemm_voc<<<4096, 256, 0, stream>>>(outs_bf, wvoc, out, b_voc);
}

// Round 17
// 1616.437 us; speedup vs baseline: 1.0132x; 1.0132x over previous
//
#include <hip/hip_runtime.h>

// ---------------------------------------------------------------------------
// AttentionDecoder. Laws:
//   R5: weights/state reads partitioned across blocks, never replicated.
//   R8: software grid barriers trash L2 -> never.
//   R9/R16: fire-and-forget gload16 staging beats reg-stage+pack (f32 direct
//           serializes loads->ds_write->barrier; pad != swizzle).
//   R12: small matvecs: full LDS stage (all gload16 in flight) + ONE barrier.
//   R14: bigger BK amortizes barrier drains.
//   R15: both-sides swizzle kills LDS bank conflicts (1.7e7 -> 0).
// R17 = R15 revert + kv BK=128 quad-chunk (32 barrier-drains for K=4096).
// ---------------------------------------------------------------------------

typedef float    f32x4 __attribute__((ext_vector_type(4)));
typedef __bf16   bf16x8 __attribute__((ext_vector_type(8)));
typedef unsigned short u16x8 __attribute__((ext_vector_type(8)));

#define DEV __device__ __forceinline__

DEV unsigned short f2bf(float f) {
  unsigned u = __builtin_bit_cast(unsigned, f);
  u += 0x7fffu + ((u >> 16) & 1u);
  return (unsigned short)(u >> 16);
}
DEV float bf2f(unsigned short h) {
  return __builtin_bit_cast(float, (unsigned)h << 16);
}
DEV bf16x8 as_bf(u16x8 v) { return __builtin_bit_cast(bf16x8, v); }
DEV u16x8 pack8(float4 a, float4 b) {
  u16x8 r;
  r[0]=f2bf(a.x); r[1]=f2bf(a.y); r[2]=f2bf(a.z); r[3]=f2bf(a.w);
  r[4]=f2bf(b.x); r[5]=f2bf(b.y); r[6]=f2bf(b.z); r[7]=f2bf(b.w);
  return r;
}
DEV void gload16(const void* g, void* l) {
  __builtin_amdgcn_global_load_lds(
      (const __attribute__((address_space(1))) void*)g,
      (__attribute__((address_space(3))) void*)l, 16, 0, 0);
}
DEV float gru1(float ir, float iz, float inn, float hr, float hz, float hn,
               float ho) {
  float r = 1.f / (1.f + expf(-(ir + hr)));
  float z = 1.f / (1.f + expf(-(iz + hz)));
  float n = tanhf(inn + r * hn);
  return (1.f - z) * n + z * ho;
}
// swizzled read offset within a [row][32]-elem chunk (gload16-staged tiles)
DEV int rdswz(int row, int fq) {
  return row * 32 + ((fq ^ ((row >> 1) & 3)) << 3);
}

// ----------------------- mega convert (one launch) --------------------------
#define NSEG 10
struct CvtSegs {
  const float* src[NSEG];
  unsigned short* dst[NSEG];
  int cum4[NSEG + 1];   // cumulative quad counts
};

__global__ __launch_bounds__(256) void k_cvt_multi(CvtSegs segs, int total4) {
  int i4 = blockIdx.x * 256 + threadIdx.x;
  if (i4 >= total4) return;
  int s = 0;
  while (i4 >= segs.cum4[s + 1]) s++;
  int off = (i4 - segs.cum4[s]) * 4;
  float4 v = *(const float4*)(segs.src[s] + off);
  unsigned short* d = segs.dst[s] + off;
  d[0] = f2bf(v.x); d[1] = f2bf(v.y); d[2] = f2bf(v.z); d[3] = f2bf(v.w);
}

// ctx_feat = [s1, s2, |s1-s2|, s1*s2]  -> bf16 [64, 16384]
__global__ __launch_bounds__(256) void k_build_ctx(const float* __restrict__ s1,
                                                   const float* __restrict__ s2,
                                                   unsigned short* __restrict__ ctx) {
  int j = blockIdx.x * 256 + threadIdx.x;
  int b = j >> 14, jj = j & 16383;
  int f = jj >> 12, k = jj & 4095;
  float a = s1[b * 4096 + k], c = s2[b * 4096 + k];
  float v = (f == 0) ? a : (f == 1) ? c : (f == 2) ? fabsf(a - c) : a * c;
  ctx[j] = f2bf(v);
}

// ---------------- fused kv GEMM, BK=128 quad-chunk + swizzle ----------------
// grid (128, 8): x = side*64 + row-block, y = col-block. EPI: tanh(+bias),
// split col 512, PERMUTED row store (tt*64+b -> b*128+tt).
__global__ __launch_bounds__(256) void k_gemm_kv(
    const unsigned short* __restrict__ enc1bf, const unsigned short* __restrict__ enc2bf,
    const unsigned short* __restrict__ wkv1, const unsigned short* __restrict__ wkv2,
    unsigned short* __restrict__ keys1, unsigned short* __restrict__ vals1,
    unsigned short* __restrict__ keys2, unsigned short* __restrict__ vals2,
    const float* __restrict__ bk1, const float* __restrict__ bv1,
    const float* __restrict__ bk2, const float* __restrict__ bv2)
{
  __shared__ __align__(16) unsigned short As[4][128 * 32];   // 32 KB
  __shared__ __align__(16) unsigned short Bs[4][128 * 32];   // 32 KB
  const int tid = threadIdx.x;
  const int side = blockIdx.x >> 6;
  const int r0 = (blockIdx.x & 63) * 128, c0 = blockIdx.y * 128;
  const unsigned short* A = side ? enc2bf : enc1bf;
  const unsigned short* B = side ? wkv2 : wkv1;
  unsigned short* kout = side ? keys2 : keys1;
  unsigned short* vout = side ? vals2 : vals1;
  const float* bk = side ? bk2 : bk1;
  const float* bv = side ? bv2 : bv1;

  const int lane = tid & 63, w = tid >> 6;
  const int wr = w >> 1, wc = w & 1;
  const int fr = lane & 15, fq = lane >> 4;
  f32x4 acc[4][4] = {};

  const int srow = tid >> 2;
  const int scol = ((tid & 3) ^ ((srow >> 1) & 3)) * 8;   // swizzled src slot
  const unsigned short* gA0 = A + (size_t)(r0 + srow) * 4096 + scol;
  const unsigned short* gA1 = A + (size_t)(r0 + 64 + srow) * 4096 + scol;
  const unsigned short* gB0 = B + (size_t)(c0 + srow) * 4096 + scol;
  const unsigned short* gB1 = B + (size_t)(c0 + 64 + srow) * 4096 + scol;

  for (int k = 0; k < 4096; k += 128) {
    #pragma unroll
    for (int c = 0; c < 4; c++) {
      gload16(gA0 + k + c * 32, As[c] + tid * 8);
      gload16(gA1 + k + c * 32, As[c] + 2048 + tid * 8);
      gload16(gB0 + k + c * 32, Bs[c] + tid * 8);
      gload16(gB1 + k + c * 32, Bs[c] + 2048 + tid * 8);
    }
    __syncthreads();

    #pragma unroll
    for (int c = 0; c < 4; c++) {
      u16x8 af[4], bfv[4];
      #pragma unroll
      for (int mi = 0; mi < 4; mi++)
        af[mi] = *(const u16x8*)&As[c][rdswz(wr * 64 + mi * 16 + fr, fq)];
      #pragma unroll
      for (int nj = 0; nj < 4; nj++)
        bfv[nj] = *(const u16x8*)&Bs[c][rdswz(wc * 64 + nj * 16 + fr, fq)];
      #pragma unroll
      for (int mi = 0; mi < 4; mi++)
        #pragma unroll
        for (int nj = 0; nj < 4; nj++)
          acc[mi][nj] = __builtin_amdgcn_mfma_f32_16x16x32_bf16(
              as_bf(af[mi]), as_bf(bfv[nj]), acc[mi][nj], 0, 0, 0);
    }
    __syncthreads();
  }

  #pragma unroll
  for (int mi = 0; mi < 4; mi++)
  #pragma unroll
  for (int nj = 0; nj < 4; nj++) {
    f32x4 a = acc[mi][nj];
    #pragma unroll
    for (int j = 0; j < 4; j++) {
      int grow = r0 + wr * 64 + mi * 16 + fq * 4 + j;
      int gcol = c0 + wc * 64 + nj * 16 + fr;
      float bias = gcol < 512 ? bk[gcol] : bv[gcol - 512];
      unsigned short r = f2bf(tanhf(a[j] + bias));
      int prow = ((grow & 63) << 7) | (grow >> 6);
      (gcol < 512 ? kout : vout)[(size_t)prow * 512 + (gcol & 511)] = r;
    }
  }
}

// ---------------- vocab GEMM, XCD remap + BK=64 + swizzle -------------------
__global__ __launch_bounds__(256) void k_gemm_voc(
    const unsigned short* __restrict__ A,       // outs_bf [2048][512]
    const unsigned short* __restrict__ B,       // wvoc [32000][512]
    float* __restrict__ of, const float* __restrict__ bias)
{
  const int L = blockIdx.x;
  const int xcd = L & 7, k = L >> 3;
  const int rb = k & 15, cb = xcd * 32 + (k >> 4);
  if (cb >= 250) return;
  const int r0 = rb * 128, c0 = cb * 128;

  __shared__ __align__(16) unsigned short As[2][128 * 32];
  __shared__ __align__(16) unsigned short Bs[2][128 * 32];
  const int tid = threadIdx.x;
  const int lane = tid & 63, w = tid >> 6;
  const int wr = w >> 1, wc = w & 1;
  const int fr = lane & 15, fq = lane >> 4;
  f32x4 acc[4][4] = {};

  const int srow = tid >> 2;
  const int scol = ((tid & 3) ^ ((srow >> 1) & 3)) * 8;
  const unsigned short* gA0 = A + (size_t)(r0 + srow) * 512 + scol;
  const unsigned short* gA1 = A + (size_t)(r0 + 64 + srow) * 512 + scol;
  const unsigned short* gB0 = B + (size_t)(c0 + srow) * 512 + scol;
  const unsigned short* gB1 = B + (size_t)(c0 + 64 + srow) * 512 + scol;

  for (int kk = 0; kk < 512; kk += 64) {
    #pragma unroll
    for (int c = 0; c < 2; c++) {
      gload16(gA0 + kk + c * 32, As[c] + tid * 8);
      gload16(gA1 + kk + c * 32, As[c] + 2048 + tid * 8);
      gload16(gB0 + kk + c * 32, Bs[c] + tid * 8);
      gload16(gB1 + kk + c * 32, Bs[c] + 2048 + tid * 8);
    }
    __syncthreads();

    #pragma unroll
    for (int c = 0; c < 2; c++) {
      u16x8 af[4], bfv[4];
      #pragma unroll
      for (int mi = 0; mi < 4; mi++)
        af[mi] = *(const u16x8*)&As[c][rdswz(wr * 64 + mi * 16 + fr, fq)];
      #pragma unroll
      for (int nj = 0; nj < 4; nj++)
        bfv[nj] = *(const u16x8*)&Bs[c][rdswz(wc * 64 + nj * 16 + fr, fq)];
      #pragma unroll
      for (int mi = 0; mi < 4; mi++)
        #pragma unroll
        for (int nj = 0; nj < 4; nj++)
          acc[mi][nj] = __builtin_amdgcn_mfma_f32_16x16x32_bf16(
              as_bf(af[mi]), as_bf(bfv[nj]), acc[mi][nj], 0, 0, 0);
    }
    __syncthreads();
  }

  #pragma unroll
  for (int mi = 0; mi < 4; mi++)
  #pragma unroll
  for (int nj = 0; nj < 4; nj++) {
    f32x4 a = acc[mi][nj];
    #pragma unroll
    for (int j = 0; j < 4; j++) {
      int grow = r0 + wr * 64 + mi * 16 + fq * 4 + j;
      int gcol = c0 + wc * 64 + nj * 16 + fr;
      of[(size_t)grow * 32000 + gcol] = a[j] + bias[gcol];
    }
  }
}

// ------------------------- h0 GEMM (A bf16, B f32) --------------------------
__global__ __launch_bounds__(256) void k_gemm_h0(
    const unsigned short* __restrict__ Ap, int lda, const float* __restrict__ Bp,
    int ldb, int M, int N, int kper, float* __restrict__ of)
{
  __shared__ __align__(16) unsigned short As[128 * 32];
  __shared__ __align__(16) unsigned short Bs[128 * 32];
  const int tid = threadIdx.x;
  const int c0 = blockIdx.x * 128, r0 = blockIdx.y * 128;
  const int k0 = blockIdx.z * kper;
  of += (size_t)blockIdx.z * M * N;

  const int lane = tid & 63, w = tid >> 6;
  const int wr = w >> 1, wc = w & 1;
  const int fr = lane & 15, fq = lane >> 4;
  f32x4 acc[4][4] = {};
  const int srow = tid >> 1, shalf = (tid & 1) * 16;

  for (int k = k0; k < k0 + kper; k += 32) {
    u16x8 a0, a1, b0, b1;
    {
      int gr = r0 + srow;
      if (gr < M) {
        const unsigned short* a = Ap + (size_t)gr * lda + k + shalf;
        a0 = *(const u16x8*)a; a1 = *(const u16x8*)(a + 8);
      } else {
        u16x8 z = {0,0,0,0,0,0,0,0}; a0 = z; a1 = z;
      }
    }
    {
      int gr = c0 + srow;
      const float* p = Bp + (size_t)gr * ldb + k + shalf;
      float4 f0 = ((const float4*)p)[0], f1 = ((const float4*)p)[1];
      float4 f2 = ((const float4*)p)[2], f3 = ((const float4*)p)[3];
      b0 = pack8(f0, f1);
      b1 = pack8(f2, f3);
    }
    *(u16x8*)&As[srow * 32 + shalf]     = a0;
    *(u16x8*)&As[srow * 32 + shalf + 8] = a1;
    *(u16x8*)&Bs[srow * 32 + shalf]     = b0;
    *(u16x8*)&Bs[srow * 32 + shalf + 8] = b1;
    __syncthreads();

    u16x8 af[4], bfv[4];
    #pragma unroll
    for (int mi = 0; mi < 4; mi++)
      af[mi] = *(const u16x8*)&As[(wr * 64 + mi * 16 + fr) * 32 + fq * 8];
    #pragma unroll
    for (int nj = 0; nj < 4; nj++)
      bfv[nj] = *(const u16x8*)&Bs[(wc * 64 + nj * 16 + fr) * 32 + fq * 8];
    #pragma unroll
    for (int mi = 0; mi < 4; mi++)
      #pragma unroll
      for (int nj = 0; nj < 4; nj++)
        acc[mi][nj] = __builtin_amdgcn_mfma_f32_16x16x32_bf16(
            as_bf(af[mi]), as_bf(bfv[nj]), acc[mi][nj], 0, 0, 0);
    __syncthreads();
  }

  #pragma unroll
  for (int mi = 0; mi < 4; mi++)
  #pragma unroll
  for (int nj = 0; nj < 4; nj++) {
    f32x4 a = acc[mi][nj];
    #pragma unroll
    for (int j = 0; j < 4; j++) {
      int grow = r0 + wr * 64 + mi * 16 + fq * 4 + j;
      int gcol = c0 + wc * 64 + nj * 16 + fr;
      if (grow < M) of[(size_t)grow * N + gcol] = a[j];
    }
  }
}

__global__ __launch_bounds__(256) void k_reduce_h0(const float* __restrict__ part,
                                                   const float* __restrict__ b_ctx,
                                                   float* __restrict__ h,
                                                   unsigned short* __restrict__ h_bf) {
  int j = blockIdx.x * 256 + threadIdx.x;   // < 64*512
  float s = b_ctx[j & 511];
  for (int z = 0; z < 8; z++) s += part[z * 32768 + j];
  h[j] = s;
  h_bf[j] = f2bf(s);
}

// ------------------- W_f = W_ih @ W_in  fold (one-time) ---------------------
__global__ __launch_bounds__(256) void k_wf(const float* __restrict__ W_ih,
                                            const float* __restrict__ W_in,
                                            unsigned short* __restrict__ wf_att,
                                            float* __restrict__ wfx) {
  __shared__ float wl[8][512];
  int ic = blockIdx.x, jc = blockIdx.y, tid = threadIdx.x;
  for (int x = tid; x < 8 * 512; x += 256)
    wl[x >> 9][x & 511] = W_ih[(ic * 8 + (x >> 9)) * 512 + (x & 511)];
  __syncthreads();
  int j = jc * 256 + tid;
  if (j >= 1324) return;
  float acc[8] = {};
  for (int d = 0; d < 512; d++) {
    float win = W_in[d * 1324 + j];
    #pragma unroll
    for (int r = 0; r < 8; r++) acc[r] += wl[r][d] * win;
  }
  for (int r = 0; r < 8; r++) {
    int i = ic * 8 + r;
    if (j < 300) wfx[i * 300 + j] = acc[r];
    else         wf_att[i * 1024 + (j - 300)] = f2bf(acc[r]);
  }
}

__global__ __launch_bounds__(256) void k_bfull(const float* __restrict__ W_ih,
                                               const float* __restrict__ b_in,
                                               const float* __restrict__ b_ih,
                                               float* __restrict__ bfull) {
  int i = blockIdx.x * 256 + threadIdx.x;
  if (i >= 1536) return;
  float acc = b_ih[i];
  for (int d = 0; d < 512; d++) acc += W_ih[i * 512 + d] * b_in[d];
  bfull[i] = acc;
}

// gi_x[t*64+b, :] = expl[t,b,:300] @ Wfx^T
__global__ __launch_bounds__(256) void k_gix(const float* __restrict__ expl,
                                             const float* __restrict__ wfx,
                                             float* __restrict__ gi_x) {
  __shared__ float el[16][300];
  int rc = blockIdx.x, ic = blockIdx.y, tid = threadIdx.x;
  for (int x = tid; x < 16 * 300; x += 256)
    el[x / 300][x % 300] = expl[(size_t)(rc * 16 + x / 300) * 300 + (x % 300)];
  __syncthreads();
  int c = ic * 256 + tid;
  float acc[16] = {};
  for (int k = 0; k < 300; k++) {
    float wv = wfx[c * 300 + k];
    #pragma unroll
    for (int r = 0; r < 16; r++) acc[r] += el[r][k] * wv;
  }
  for (int r = 0; r < 16; r++) gi_x[(size_t)(rc * 16 + r) * 1536 + c] = acc[r];
}

// ---- S1: [q|gh] matvec, fully staged + swizzle, ONE barrier ----------------
__global__ __launch_bounds__(256) void k_mv64f(
    const unsigned short* __restrict__ A,      // h_bf [64][512]
    const unsigned short* __restrict__ B,      // wcat [2560][512]
    const float* __restrict__ bq1, const float* __restrict__ bq2,
    const float* __restrict__ b_hh,
    float* __restrict__ qf, float* __restrict__ ghf)
{
  __shared__ __align__(16) unsigned short AL[16 * 2048];   // 64KB
  __shared__ __align__(16) unsigned short BL[16 * 2048];   // 64KB
  const int tid = threadIdx.x;
  const int n0 = blockIdx.x * 64;
  const int srow = tid >> 2;
  const int scol = ((tid & 3) ^ ((srow >> 1) & 3)) * 8;

  #pragma unroll
  for (int c = 0; c < 16; c++) {
    gload16(A + (size_t)srow * 512 + c * 32 + scol, AL + c * 2048 + tid * 8);
    gload16(B + (size_t)(n0 + srow) * 512 + c * 32 + scol, BL + c * 2048 + tid * 8);
  }
  __syncthreads();

  const int lane = tid & 63, w = tid >> 6;
  const int fr = lane & 15, fq = lane >> 4;
  f32x4 acc[4] = {};
  #pragma unroll
  for (int c = 0; c < 16; c++) {
    u16x8 af = *(const u16x8*)(AL + c * 2048 + rdswz(w * 16 + fr, fq));
    #pragma unroll
    for (int nj = 0; nj < 4; nj++) {
      u16x8 bv = *(const u16x8*)(BL + c * 2048 + rdswz(nj * 16 + fr, fq));
      acc[nj] = __builtin_amdgcn_mfma_f32_16x16x32_bf16(as_bf(af), as_bf(bv), acc[nj], 0, 0, 0);
    }
  }
  #pragma unroll
  for (int nj = 0; nj < 4; nj++) {
    #pragma unroll
    for (int j = 0; j < 4; j++) {
      int row = w * 16 + fq * 4 + j;
      int col = n0 + nj * 16 + fr;
      float v = acc[nj][j];
      if (col < 512)       qf[(size_t)row * 1024 + col] = tanhf(v + bq1[col]);
      else if (col < 1024) qf[(size_t)row * 1024 + col] = tanhf(v + bq2[col - 512]);
      else                 ghf[(size_t)row * 1536 + (col - 1024)] = v + b_hh[col - 1024];
    }
  }
}

// ------------------- S2: attention (R6 verbatim) ----------------------------
__global__ __launch_bounds__(256) void k_att(
    const float* __restrict__ qf,
    const unsigned short* __restrict__ keys1, const unsigned short* __restrict__ keys2,
    const unsigned short* __restrict__ vals1, const unsigned short* __restrict__ vals2,
    unsigned short* __restrict__ att_bf)
{
  const int id = blockIdx.x, side = id >> 6, b = id & 63;
  const int tid = threadIdx.x;
  __shared__ float qv[512];
  __shared__ float sred[128][2];
  __shared__ float pr[128];

  for (int i = tid; i < 512; i += 256)
    qv[i] = qf[(size_t)b * 1024 + side * 512 + i];
  __syncthreads();

  const unsigned short* keys = side ? keys2 : keys1;
  {
    int tt = tid >> 1, half = tid & 1;
    const u16x8* krow = (const u16x8*)(keys + ((size_t)(b * 128 + tt)) * 512 + half * 256);
    float acc = 0.f;
    #pragma unroll 4
    for (int k8 = 0; k8 < 32; k8++) {
      u16x8 kv = krow[k8];
      #pragma unroll
      for (int jj = 0; jj < 8; jj++) acc += qv[half * 256 + k8 * 8 + jj] * bf2f(kv[jj]);
    }
    sred[tt][half] = acc;
  }
  __syncthreads();

  if (tid < 64) {
    float s0 = sred[tid][0] + sred[tid][1];
    float s1 = sred[tid + 64][0] + sred[tid + 64][1];
    float m = fmaxf(s0, s1);
    #pragma unroll
    for (int off = 32; off; off >>= 1) m = fmaxf(m, __shfl_xor(m, off));
    float e0 = __expf(s0 - m), e1 = __expf(s1 - m);
    float ss = e0 + e1;
    #pragma unroll
    for (int off = 32; off; off >>= 1) ss += __shfl_xor(ss, off);
    float inv = 1.f / ss;
    pr[tid] = e0 * inv;
    pr[tid + 64] = e1 * inv;
  }
  __syncthreads();

  const unsigned short* vals = side ? vals2 : vals1;
  {
    int a0 = tid * 2;
    float acc0 = 0.f, acc1 = 0.f;
    for (int tt = 0; tt < 128; tt++) {
      float p = pr[tt];
      unsigned v = *(const unsigned*)(vals + ((size_t)(b * 128 + tt)) * 512 + a0);
      acc0 += p * bf2f((unsigned short)(v & 0xffffu));
      acc1 += p * bf2f((unsigned short)(v >> 16));
    }
    att_bf[(size_t)b * 1024 + side * 512 + a0]     = f2bf(acc0);
    att_bf[(size_t)b * 1024 + side * 512 + a0 + 1] = f2bf(acc1);
  }
}

// ---- S3: gi partials, split-K (2x24), fully staged + swizzle ---------------
__global__ __launch_bounds__(256) void k_giK(
    const unsigned short* __restrict__ att_bf,   // [64][1024]
    const unsigned short* __restrict__ wf_att,   // [1536][1024]
    float* __restrict__ gip)
{
  __shared__ __align__(16) unsigned short AL[16 * 2048];
  __shared__ __align__(16) unsigned short BL[16 * 2048];
  const int tid = threadIdx.x;
  const int j = blockIdx.x % 24, kh = blockIdx.x / 24;
  const int n0 = j * 64, k0 = kh * 512;
  const int srow = tid >> 2;
  const int scol = ((tid & 3) ^ ((srow >> 1) & 3)) * 8;

  #pragma unroll
  for (int c = 0; c < 16; c++) {
    gload16(att_bf + (size_t)srow * 1024 + k0 + c * 32 + scol, AL + c * 2048 + tid * 8);
    gload16(wf_att + (size_t)(n0 + srow) * 1024 + k0 + c * 32 + scol, BL + c * 2048 + tid * 8);
  }
  __syncthreads();

  const int lane = tid & 63, w = tid >> 6;
  const int fr = lane & 15, fq = lane >> 4;
  f32x4 acc[4] = {};
  #pragma unroll
  for (int c = 0; c < 16; c++) {
    u16x8 af = *(const u16x8*)(AL + c * 2048 + rdswz(w * 16 + fr, fq));
    #pragma unroll
    for (int nj = 0; nj < 4; nj++) {
      u16x8 bv = *(const u16x8*)(BL + c * 2048 + rdswz(nj * 16 + fr, fq));
      acc[nj] = __builtin_amdgcn_mfma_f32_16x16x32_bf16(as_bf(af), as_bf(bv), acc[nj], 0, 0, 0);
    }
  }
  #pragma unroll
  for (int nj = 0; nj < 4; nj++) {
    #pragma unroll
    for (int jj = 0; jj < 4; jj++) {
      int row = w * 16 + fq * 4 + jj;
      int col = n0 + nj * 16 + fr;
      gip[(size_t)(kh * 64 + row) * 1536 + col] = acc[nj][jj];
    }
  }
}

// ---- S4: combine partials + GRU (R12 verbatim) -----------------------------
__global__ __launch_bounds__(512) void k_gru2(
    int t, const float* __restrict__ gip, const float* __restrict__ gi_x,
    const float* __restrict__ bfull, const float* __restrict__ ghf,
    float* __restrict__ hst, unsigned short* __restrict__ h_bf,
    unsigned short* __restrict__ outs_bf)
{
  const int b = blockIdx.x, d = threadIdx.x;
  size_t gb = (size_t)(t * 64 + b) * 1536;
  float ir = gip[(size_t)b * 1536 + d] + gip[(size_t)(64 + b) * 1536 + d]
           + gi_x[gb + d] + bfull[d];
  float iz = gip[(size_t)b * 1536 + 512 + d] + gip[(size_t)(64 + b) * 1536 + 512 + d]
           + gi_x[gb + 512 + d] + bfull[512 + d];
  float inn = gip[(size_t)b * 1536 + 1024 + d] + gip[(size_t)(64 + b) * 1536 + 1024 + d]
           + gi_x[gb + 1024 + d] + bfull[1024 + d];
  float hv = gru1(ir, iz, inn,
                  ghf[b * 1536 + d], ghf[b * 1536 + 512 + d], ghf[b * 1536 + 1024 + d],
                  hst[b * 512 + d]);
  hst[b * 512 + d] = hv;
  unsigned short bf = f2bf(hv);
  h_bf[b * 512 + d] = bf;
  outs_bf[(size_t)(t * 64 + b) * 512 + d] = bf;
}

// ---------------------------------------------------------------------------
extern "C" void kernel_launch(void* const* d_in, const int* in_sizes, int n_in,
                              void* d_out, int out_size, void* d_ws, size_t ws_size,
                              hipStream_t stream) {
  const float* expl  = (const float*)d_in[0];
  const float* enc1  = (const float*)d_in[1];
  const float* enc2  = (const float*)d_in[2];
  const float* s1e   = (const float*)d_in[3];
  const float* s2e   = (const float*)d_in[4];
  const float* W_ctx = (const float*)d_in[5];
  const float* b_ctx = (const float*)d_in[6];
  const float* Wq1   = (const float*)d_in[7];
  const float* bq1   = (const float*)d_in[8];
  const float* Wk1   = (const float*)d_in[9];
  const float* bk1   = (const float*)d_in[10];
  const float* Wv1   = (const float*)d_in[11];
  const float* bv1   = (const float*)d_in[12];
  const float* Wq2   = (const float*)d_in[13];
  const float* bq2   = (const float*)d_in[14];
  const float* Wk2   = (const float*)d_in[15];
  const float* bk2   = (const float*)d_in[16];
  const float* Wv2   = (const float*)d_in[17];
  const float* bv2   = (const float*)d_in[18];
  const float* W_in  = (const float*)d_in[19];
  const float* b_in  = (const float*)d_in[20];
  const float* W_ih  = (const float*)d_in[21];
  const float* b_ih  = (const float*)d_in[22];
  const float* W_hh  = (const float*)d_in[23];
  const float* b_hh  = (const float*)d_in[24];
  const float* W_voc = (const float*)d_in[25];
  const float* b_voc = (const float*)d_in[26];
  float* out = (float*)d_out;

  char* ws = (char*)d_ws;
  unsigned short* keys1  = (unsigned short*)(ws + 0);
  unsigned short* vals1  = (unsigned short*)(ws + 8388608);
  unsigned short* keys2  = (unsigned short*)(ws + 16777216);
  unsigned short* vals2  = (unsigned short*)(ws + 25165824);
  unsigned short* encbf1 = (unsigned short*)(ws + 33554432);   // 67.1 MB
  unsigned short* encbf2 = (unsigned short*)(ws + 100663296);  // 67.1 MB
  unsigned short* wkv1   = (unsigned short*)(ws + 167772160);  // 8.4 MB
  unsigned short* wkv2   = (unsigned short*)(ws + 176160768);  // 8.4 MB
  unsigned short* wvoc   = (unsigned short*)(ws + 184549376);  // 32.8 MB
  unsigned short* wcat   = (unsigned short*)(ws + 217317376);  // [2560][512]
  unsigned short* wf_att = (unsigned short*)(ws + 219938816);  // [1536][1024]
  float*          wfx    = (float*)(ws + 223084544);
  float*          bfull  = (float*)(ws + 224927744);
  float*          gi_x   = (float*)(ws + 224933888);           // 12.6 MB
  unsigned short* ctx_bf = (unsigned short*)(ws + 237516800);
  float*          part   = (float*)(ws + 239613952);
  float*          hst    = (float*)(ws + 240662528);
  unsigned short* h_bf   = (unsigned short*)(ws + 240793600);
  float*          qf     = (float*)(ws + 240859136);
  float*          ghf    = (float*)(ws + 241121280);
  unsigned short* att_bf = (unsigned short*)(ws + 241514496);
  unsigned short* outs_bf= (unsigned short*)(ws + 241645568);
  float*          gip    = (float*)(ws + 243742720);
  // end ~244.5 MB

  // ---- ONE mega-convert for every f32->bf16 segment ----
  {
    CvtSegs segs;
    const float* srcs[NSEG] = { enc1, enc2, Wk1, Wv1, Wk2, Wv2, W_voc,
                                Wq1, Wq2, W_hh };
    unsigned short* dsts[NSEG] = { encbf1, encbf2, wkv1, wkv1 + 512*4096,
                                   wkv2, wkv2 + 512*4096, wvoc,
                                   wcat, wcat + 512*512, wcat + 1024*512 };
    int ns[NSEG] = { 8192*4096, 8192*4096, 512*4096, 512*4096, 512*4096,
                     512*4096, 32000*512, 512*512, 512*512, 1536*512 };
    int cum = 0;
    for (int s = 0; s < NSEG; s++) {
      segs.src[s] = srcs[s]; segs.dst[s] = dsts[s];
      segs.cum4[s] = cum; cum += ns[s] / 4;
    }
    segs.cum4[NSEG] = cum;
    k_cvt_multi<<<(cum + 255) / 256, 256, 0, stream>>>(segs, cum);
  }

  // ---- fused kv GEMM (both sides, one dispatch, BK=128 + swizzle) ----
  k_gemm_kv<<<dim3(128, 8), 256, 0, stream>>>(
      encbf1, encbf2, wkv1, wkv2, keys1, vals1, keys2, vals2,
      bk1, bv1, bk2, bv2);

  // ---- Wf fold + gi_x ----
  k_wf<<<dim3(192, 6), 256, 0, stream>>>(W_ih, W_in, wf_att, wfx);
  k_bfull<<<6, 256, 0, stream>>>(W_ih, b_in, b_ih, bfull);
  k_gix<<<dim3(128, 6), 256, 0, stream>>>(expl, wfx, gi_x);

  // ---- h0 ----
  k_build_ctx<<<4096, 256, 0, stream>>>(s1e, s2e, ctx_bf);
  k_gemm_h0<<<dim3(4, 1, 8), 256, 0, stream>>>(
      ctx_bf, 16384, W_ctx, 16384, 64, 512, 2048, part);
  k_reduce_h0<<<128, 256, 0, stream>>>(part, b_ctx, hst, h_bf);

  // ---- recurrence: 4 launches per step (R12 chain + swizzle) ----
  for (int t = 0; t < 32; t++) {
    k_mv64f<<<40, 256, 0, stream>>>(h_bf, wcat, bq1, bq2, b_hh, qf, ghf);
    k_att<<<128, 256, 0, stream>>>(qf, keys1, keys2, vals1, vals2, att_bf);
    k_giK<<<48, 256, 0, stream>>>(att_bf, wf_att, gip);
    k_gru2<<<64, 512, 0, stream>>>(t, gip, gi_x, bfull, ghf, hst, h_bf, outs_bf);
  }

  // ---- logits = outs @ W_voc^T + b_voc (XCD-remapped, BK=64 + swizzle) ----
  k_gemm_voc<<<4096, 256, 0, stream>>>(outs_bf, wvoc, out, b_voc);
}